// Round 4
// baseline (439.850 us; speedup 1.0000x reference)
//
#include <hip/hip_runtime.h>

// Causal attention fwd: B=1, H=16, S=2048, D=128, fp32 in/out.
// Flash-style, bf16 MFMA 16x16x32, swapped-QK^T so P^T stays in-register.

#define NH  16
#define SEQ 2048
#define DIM 128
#define SCALE 0.08838834764831845f  // 1/sqrt(128)

typedef __attribute__((ext_vector_type(8))) short    bf16x8;
typedef __attribute__((ext_vector_type(4))) short    short4v;
typedef __attribute__((ext_vector_type(4))) float    f32x4;
typedef __attribute__((ext_vector_type(8))) unsigned short ushort8;

__device__ __forceinline__ unsigned short f2bf(float f) {
    unsigned u = __builtin_bit_cast(unsigned, f);
    u += 0x7FFFu + ((u >> 16) & 1u);   // RNE
    return (unsigned short)(u >> 16);
}

// ---------------- prepass: fp32 -> bf16 (Q, K) ----------------
__global__ void cvt_kernel(const float* __restrict__ in, unsigned short* __restrict__ out) {
    const int i = blockIdx.x * blockDim.x + threadIdx.x;     // 0..524287, exact
    const float4* p = reinterpret_cast<const float4*>(in) + (size_t)i * 2;
    const float4 a = p[0], b = p[1];
    ushort8 o;
    o[0]=f2bf(a.x); o[1]=f2bf(a.y); o[2]=f2bf(a.z); o[3]=f2bf(a.w);
    o[4]=f2bf(b.x); o[5]=f2bf(b.y); o[6]=f2bf(b.z); o[7]=f2bf(b.w);
    reinterpret_cast<ushort8*>(out)[i] = o;
}

// ---------------- prepass: V fp32 [S][D] -> bf16 V^T [D][S] ----------------
__global__ void vt_kernel(const float* __restrict__ V, unsigned short* __restrict__ VT) {
    __shared__ unsigned short t[64][68];                     // 68: 2-way bank alias only (free)
    const int s0 = blockIdx.x * 64;
    const int d0 = blockIdx.y * 64;
    const size_t hi  = (size_t)blockIdx.z * SEQ * DIM;
    const size_t hoT = (size_t)blockIdx.z * DIM * SEQ;
    const int tx = threadIdx.x & 63;
    const int ty = threadIdx.x >> 6;
#pragma unroll
    for (int i = 0; i < 16; ++i) {
        const int r = ty * 16 + i;
        t[r][tx] = f2bf(V[hi + (size_t)(s0 + r) * DIM + d0 + tx]);
    }
    __syncthreads();
#pragma unroll
    for (int i = 0; i < 16; ++i) {
        const int r = ty * 16 + i;
        VT[hoT + (size_t)(d0 + r) * SEQ + s0 + tx] = t[tx][r];
    }
}

// ---------------- main attention kernel ----------------
// One wave handles 16 q-rows of one head. S^T = mfma(K, Q): acc col = q (lane&15),
// acc row = key ((lane>>4)*4 + r). P^T regs are then directly the B-operand of
// O^T = mfma(V^T, P^T) (key mapping kappa(g,e) = 16*(e>>2) + g*4 + (e&3)).
template<bool PRE>
__global__ __launch_bounds__(256, 2) void attn_fwd(
    const float* __restrict__ Qf, const float* __restrict__ Kf, const float* __restrict__ Vf,
    const unsigned short* __restrict__ Qb, const unsigned short* __restrict__ Kb,
    const unsigned short* __restrict__ VTb, float* __restrict__ O)
{
    const int lane = threadIdx.x & 63;
    const int wid  = threadIdx.x >> 6;
    const int l15  = lane & 15;
    const int lg   = lane >> 4;
    const int head = blockIdx.y;
    const int qt   = gridDim.x - 1 - blockIdx.x;             // heavy tiles dispatched first
    const int qbase = qt * 64 + wid * 16;
    const int qmax  = qbase + 15;
    const size_t ho  = (size_t)head * SEQ * DIM;
    const size_t hoT = (size_t)head * DIM * SEQ;

    // Q fragments (B operand), d-mapping kappa_d(g,e) = g*8 + e within each 32-d block
    bf16x8 qfrag[4];
    if constexpr (PRE) {
        const unsigned short* qrow = Qb + ho + (size_t)(qbase + l15) * DIM;
#pragma unroll
        for (int mi = 0; mi < 4; ++mi)
            qfrag[mi] = *reinterpret_cast<const bf16x8*>(qrow + mi * 32 + lg * 8);
    } else {
        const float* qrow = Qf + ho + (size_t)(qbase + l15) * DIM;
#pragma unroll
        for (int mi = 0; mi < 4; ++mi) {
            const float4 a = *reinterpret_cast<const float4*>(qrow + mi * 32 + lg * 8);
            const float4 b = *reinterpret_cast<const float4*>(qrow + mi * 32 + lg * 8 + 4);
            bf16x8 f;
            f[0]=(short)f2bf(a.x); f[1]=(short)f2bf(a.y); f[2]=(short)f2bf(a.z); f[3]=(short)f2bf(a.w);
            f[4]=(short)f2bf(b.x); f[5]=(short)f2bf(b.y); f[6]=(short)f2bf(b.z); f[7]=(short)f2bf(b.w);
            qfrag[mi] = f;
        }
    }

    f32x4 oacc[8];
#pragma unroll
    for (int i = 0; i < 8; ++i) oacc[i] = f32x4{0.f, 0.f, 0.f, 0.f};
    float m_run = -INFINITY, l_run = 0.f;

    for (int kb = 0; kb <= qmax; kb += 32) {
        // ---- S^T tile: keys kb..kb+31 (two 16-row MFMA accs), cols = q ----
        f32x4 sT0 = f32x4{0.f,0.f,0.f,0.f}, sT1 = f32x4{0.f,0.f,0.f,0.f};
        if constexpr (PRE) {
            const unsigned short* k0 = Kb + ho + (size_t)(kb + l15) * DIM;
            const unsigned short* k1 = k0 + 16 * DIM;
#pragma unroll
            for (int mi = 0; mi < 4; ++mi) {
                const bf16x8 ka = *reinterpret_cast<const bf16x8*>(k0 + mi * 32 + lg * 8);
                sT0 = __builtin_amdgcn_mfma_f32_16x16x32_bf16(ka, qfrag[mi], sT0, 0, 0, 0);
                const bf16x8 kc = *reinterpret_cast<const bf16x8*>(k1 + mi * 32 + lg * 8);
                sT1 = __builtin_amdgcn_mfma_f32_16x16x32_bf16(kc, qfrag[mi], sT1, 0, 0, 0);
            }
        } else {
            const float* k0 = Kf + ho + (size_t)(kb + l15) * DIM;
            const float* k1 = k0 + 16 * DIM;
#pragma unroll
            for (int mi = 0; mi < 4; ++mi) {
                float4 a = *reinterpret_cast<const float4*>(k0 + mi * 32 + lg * 8);
                float4 b = *reinterpret_cast<const float4*>(k0 + mi * 32 + lg * 8 + 4);
                bf16x8 f;
                f[0]=(short)f2bf(a.x); f[1]=(short)f2bf(a.y); f[2]=(short)f2bf(a.z); f[3]=(short)f2bf(a.w);
                f[4]=(short)f2bf(b.x); f[5]=(short)f2bf(b.y); f[6]=(short)f2bf(b.z); f[7]=(short)f2bf(b.w);
                sT0 = __builtin_amdgcn_mfma_f32_16x16x32_bf16(f, qfrag[mi], sT0, 0, 0, 0);
                a = *reinterpret_cast<const float4*>(k1 + mi * 32 + lg * 8);
                b = *reinterpret_cast<const float4*>(k1 + mi * 32 + lg * 8 + 4);
                f[0]=(short)f2bf(a.x); f[1]=(short)f2bf(a.y); f[2]=(short)f2bf(a.z); f[3]=(short)f2bf(a.w);
                f[4]=(short)f2bf(b.x); f[5]=(short)f2bf(b.y); f[6]=(short)f2bf(b.z); f[7]=(short)f2bf(b.w);
                sT1 = __builtin_amdgcn_mfma_f32_16x16x32_bf16(f, qfrag[mi], sT1, 0, 0, 0);
            }
        }

        // ---- scale + causal mask ----
        float s[8];
#pragma unroll
        for (int r = 0; r < 4; ++r) { s[r] = sT0[r] * SCALE; s[4 + r] = sT1[r] * SCALE; }
        // Mask whenever this tile reaches past ANY of this wave's diagonals
        // (q in [qbase, qbase+15]) — i.e. kb+31 > qbase. NOT qmax: waves with
        // qbase ≡ 16 (mod 32) have their diagonal inside a tile whose end
        // equals qmax exactly, which the old qmax-gate skipped (absmax 1.46 bug).
        if (kb + 31 > qbase) {
            const int qg = qbase + l15;
#pragma unroll
            for (int r = 0; r < 4; ++r) {
                if (kb + lg * 4 + r > qg)      s[r]     = -1e30f;
                if (kb + 16 + lg * 4 + r > qg) s[4 + r] = -1e30f;
            }
        }

        // ---- online softmax (row = q = lane&15; reduce over regs + lanes ^16 ^32) ----
        float mt = s[0];
#pragma unroll
        for (int i = 1; i < 8; ++i) mt = fmaxf(mt, s[i]);
        mt = fmaxf(mt, __shfl_xor(mt, 16));
        mt = fmaxf(mt, __shfl_xor(mt, 32));
        const float m_new = fmaxf(m_run, mt);
        const float alpha = __expf(m_run - m_new);
        float p[8], psum = 0.f;
#pragma unroll
        for (int i = 0; i < 8; ++i) { p[i] = __expf(s[i] - m_new); psum += p[i]; }
        psum += __shfl_xor(psum, 16);
        psum += __shfl_xor(psum, 32);
        l_run = l_run * alpha + psum;
        m_run = m_new;
#pragma unroll
        for (int i = 0; i < 8; ++i) {
            oacc[i][0] *= alpha; oacc[i][1] *= alpha; oacc[i][2] *= alpha; oacc[i][3] *= alpha;
        }
        bf16x8 pf;
#pragma unroll
        for (int i = 0; i < 8; ++i) pf[i] = (short)f2bf(p[i]);

        // ---- O^T += V^T x P^T  (A = V^T fragment, key mapping kappa(g,e)) ----
#pragma unroll
        for (int db = 0; db < 8; ++db) {
            bf16x8 vf;
            if constexpr (PRE) {
                const unsigned short* vrow = VTb + hoT + (size_t)(db * 16 + l15) * SEQ + kb;
                const short4v v0 = *reinterpret_cast<const short4v*>(vrow + lg * 4);
                const short4v v1 = *reinterpret_cast<const short4v*>(vrow + 16 + lg * 4);
                vf[0]=v0[0]; vf[1]=v0[1]; vf[2]=v0[2]; vf[3]=v0[3];
                vf[4]=v1[0]; vf[5]=v1[1]; vf[6]=v1[2]; vf[7]=v1[3];
            } else {
#pragma unroll
                for (int e = 0; e < 8; ++e) {
                    const int key = kb + 16 * (e >> 2) + lg * 4 + (e & 3);
                    vf[e] = (short)f2bf(Vf[ho + (size_t)key * DIM + db * 16 + l15]);
                }
            }
            oacc[db] = __builtin_amdgcn_mfma_f32_16x16x32_bf16(vf, pf, oacc[db], 0, 0, 0);
        }
    }

    // ---- epilogue: O[q][d] = O^T acc / l_run ----
    const float inv = 1.f / l_run;
    float* orow = O + ho + (size_t)(qbase + l15) * DIM;
#pragma unroll
    for (int db = 0; db < 8; ++db) {
        const float4 o{oacc[db][0] * inv, oacc[db][1] * inv, oacc[db][2] * inv, oacc[db][3] * inv};
        *reinterpret_cast<float4*>(orow + db * 16 + lg * 4) = o;
    }
}

extern "C" void kernel_launch(void* const* d_in, const int* in_sizes, int n_in,
                              void* d_out, int out_size, void* d_ws, size_t ws_size,
                              hipStream_t stream) {
    const float* Q = (const float*)d_in[0];
    const float* K = (const float*)d_in[1];
    const float* V = (const float*)d_in[2];
    float* O = (float*)d_out;

    const size_t ELEMS = (size_t)NH * SEQ * DIM;           // 4,194,304
    const size_t NEED  = 3 * ELEMS * sizeof(unsigned short); // 24 MiB

    if (ws_size >= NEED) {
        unsigned short* Qb = (unsigned short*)d_ws;
        unsigned short* Kb = Qb + ELEMS;
        unsigned short* VT = Kb + ELEMS;
        cvt_kernel<<<dim3(ELEMS / 8 / 256), dim3(256), 0, stream>>>(Q, Qb);
        cvt_kernel<<<dim3(ELEMS / 8 / 256), dim3(256), 0, stream>>>(K, Kb);
        vt_kernel<<<dim3(SEQ / 64, DIM / 64, NH), dim3(256), 0, stream>>>(V, VT);
        attn_fwd<true><<<dim3(SEQ / 64, NH), dim3(256), 0, stream>>>(
            nullptr, nullptr, nullptr, Qb, Kb, VT, O);
    } else {
        attn_fwd<false><<<dim3(SEQ / 64, NH), dim3(256), 0, stream>>>(
            Q, K, V, nullptr, nullptr, nullptr, O);
    }
}